// Round 4
// baseline (374.344 us; speedup 1.0000x reference)
//
#include <hip/hip_runtime.h>
#include <math.h>

#define BB 4096
#define SEQ 50
#define KK 4
#define HH 64
#define NCOL (KK*SEQ)      // 200
#define NPART 64           // partial-sum groups over batch
#define BPP (BB/NPART)     // 64 batches per group

__device__ __forceinline__ float readlane_f32(float v, int lane) {
    return __int_as_float(__builtin_amdgcn_readlane(__float_as_int(v), lane));
}

// ---------------------------------------------------------------------------
// INIT: partial softmax denominators for iteration 0 (unshifted exp: |cw|
// stays < ~30 across iterations, exp fits fp32 comfortably) + zero the
// iter-1/2 partial accumulators. grid = NPART x 256; thread t < NCOL owns
// column t (coalesced across t).   [verbatim from the round-0 verified kernel]
// ---------------------------------------------------------------------------
__global__ void init_kernel(const float* __restrict__ cw,
                            float* __restrict__ part0,
                            float* __restrict__ part1,
                            float* __restrict__ part2) {
    const int p = blockIdx.x;
    const int t = threadIdx.x;
    if (t < NCOL) {
        const float* row = cw + (size_t)p * BPP * NCOL + t;
        float s = 0.f;
#pragma unroll 8
        for (int b = 0; b < BPP; b++) s += __expf(row[b * NCOL]);
        part0[p * NCOL + t] = s;
        part1[p * NCOL + t] = 0.f;
        part2[p * NCOL + t] = 0.f;
    }
}

// ---------------------------------------------------------------------------
// UPDATE: one routing iteration. grid = BB x 256; wave = k, lane = h.
// Math is byte-identical to the round-0 verified kernel. Only change:
// x is RE-READ in the delta phase (same addresses, L1/L2-hot, x is never
// written -> identical values) instead of keeping xrow[50] live across the
// whole kernel. Compiler barrier prevents CSE from re-materializing the
// 50 long-lived registers. Peak VGPR ~190 -> ~128, occupancy 2x.
// ---------------------------------------------------------------------------
template <int ITER>   // 0,1 = routing update; 2 = final (writes out)
__global__ __launch_bounds__(256, 4)
void update_kernel(const float* __restrict__ cw_src,
                   float* __restrict__ cw_dst,
                   const float* __restrict__ x,
                   const int* __restrict__ mask,
                   const float* __restrict__ part_in,
                   float* __restrict__ part_out,
                   float* __restrict__ out) {
    const int b = blockIdx.x;
    const int k = threadIdx.x >> 6;
    const int h = threadIdx.x & 63;

    __shared__ float scol[NCOL];

    // column denominators: thread t < NCOL sums NPART partials (L2-hot)
    if (threadIdx.x < NCOL) {
        float s = 0.f;
#pragma unroll 16
        for (int p = 0; p < NPART; p++) s += part_in[p * NCOL + threadIdx.x];
        scol[threadIdx.x] = s;
    }
    __syncthreads();

    // lane s < SEQ: w_s = mask ? exp(c)/colsum : 0
    float wlane = 0.f, c = 0.f;
    if (h < SEQ) {
        c = cw_src[(size_t)b * NCOL + k * SEQ + h];
        float e = __expf(c) / scol[k * SEQ + h];
        wlane = (mask[b * SEQ + h] != 0) ? e : 0.f;
    }

    // v_h = sum_s w_s * x[b,s,k,h] ; w_s broadcast via readlane (SALU path).
    // x read streaming (coalesced 256 B per wave-load), not register-cached.
    const float* xp = x + (size_t)b * (SEQ * KK * HH) + k * HH + h;
    float v = 0.f;
#pragma unroll
    for (int s = 0; s < SEQ; s++)
        v = fmaf(readlane_f32(wlane, s), xp[s * (KK * HH)], v);

    // squash: n2 = ||v||^2 (6 shfls)
    float n2 = v * v;
#pragma unroll
    for (int off = 32; off >= 1; off >>= 1) n2 += __shfl_xor(n2, off, 64);
    const float scalar = n2 / ((1.f + n2) * sqrtf(n2 + 1e-9f));
    v *= scalar;

    if (ITER == 2) {
        out[(size_t)b * (KK * HH) + k * HH + h] = v;
    } else {
        // Compiler barrier: force the delta phase to RE-LOAD x (L1/L2-hot)
        // rather than CSE-ing with the v-loop loads (which would keep 50
        // VGPRs live across the butterfly). Values identical: x is const.
        asm volatile("" ::: "memory");

        // delta_s = sum_h x[s,h]*v_h for all s at once: reduce-scatter
        // butterfly. cur[i] starts as P[s=i][this lane] = x[b,i,k,h]*v.
        float cur[64];
#pragma unroll
        for (int s = 0; s < SEQ; s++) cur[s] = xp[s * (KK * HH)] * v;
#pragma unroll
        for (int s = SEQ; s < 64; s++) cur[s] = 0.f;

#pragma unroll
        for (int j = 0; j < 6; j++) {
            const int half = 32 >> j;
            const bool hi = (h >> j) & 1;
            float nxt[32];
#pragma unroll
            for (int i = 0; i < 32; i++) {
                if (i < half) {
                    float keep = hi ? cur[2 * i + 1] : cur[2 * i];
                    float send = hi ? cur[2 * i] : cur[2 * i + 1];
                    float recv = __shfl_xor(send, 1 << j, 64);
                    nxt[i] = keep + recv;
                }
            }
#pragma unroll
            for (int i = 0; i < 32; i++) {
                if (i < half) cur[i] = nxt[i];
            }
        }
        // lane s now holds delta_s
        if (h < SEQ) {
            const float nc = c + cur[0];
            cw_dst[(size_t)b * NCOL + k * SEQ + h] = nc;
            atomicAdd(&part_out[(b >> 6) * NCOL + k * SEQ + h], __expf(nc));
        }
    }
}

extern "C" void kernel_launch(void* const* d_in, const int* in_sizes, int n_in,
                              void* d_out, int out_size, void* d_ws, size_t ws_size,
                              hipStream_t stream) {
    const int*   mask  = (const int*)d_in[0];
    const float* x     = (const float*)d_in[1];
    const float* cw_in = (const float*)d_in[2];
    float* out = (float*)d_out;

    float* cw_ws = (float*)d_ws;                       // BB*NCOL floats
    float* part0 = cw_ws + (size_t)BB * NCOL;          // NPART*NCOL
    float* part1 = part0 + NPART * NCOL;
    float* part2 = part1 + NPART * NCOL;

    init_kernel<<<NPART, 256, 0, stream>>>(cw_in, part0, part1, part2);
    update_kernel<0><<<BB, 256, 0, stream>>>(cw_in, cw_ws, x, mask, part0, part1, nullptr);
    update_kernel<1><<<BB, 256, 0, stream>>>(cw_ws, cw_ws, x, mask, part1, part2, nullptr);
    update_kernel<2><<<BB, 256, 0, stream>>>(cw_ws, nullptr, x, mask, part2, nullptr, out);
}